// Round 7
// baseline (1382.595 us; speedup 1.0000x reference)
//
#include <hip/hip_runtime.h>

#define N_NODES 100000
#define N1 (N_NODES + 1)
#define N_EDGES 3200000
#define N_GRAPHS 1000
#define IN_DIM 10
#define HIDDEN 64
#define NQUADS (N_NODES / 4)   // 25000 exact
#define QNB (NQUADS / 4)       // 6250 blocks per gather pass (4 quads/block)

#define NRANGES 8
#define RANGE_SIZE ((N_NODES + NRANGES - 1) / NRANGES)
#define CHUNK_EDGES 4096

#define SLICE (N1 * 8)         // floats per 8-dim slice table

typedef float f32x4 __attribute__((ext_vector_type(4)));

// ---------------- degree histogram ----------------
__global__ void k_deg(const int* __restrict__ col, int* __restrict__ deg) {
    int e = blockIdx.x * blockDim.x + threadIdx.x;
    if (e < N_EDGES) atomicAdd(&deg[col[e]], 1);
}

// ---------------- hierarchical exclusive scan (offsets) ----------------
__global__ __launch_bounds__(1024) void k_scan_block(const int* __restrict__ deg,
                                                     int* __restrict__ offs,
                                                     int* __restrict__ bsums) {
    __shared__ int s[1024];
    int t = threadIdx.x;
    int i = blockIdx.x * 1024 + t;
    int v = (i < N_NODES) ? deg[i] : 0;
    s[t] = v;
    __syncthreads();
    for (int d = 1; d < 1024; d <<= 1) {
        int x = (t >= d) ? s[t - d] : 0;
        __syncthreads();
        s[t] += x;
        __syncthreads();
    }
    if (i < N_NODES) offs[i] = s[t] - v;
    if (t == 1023) bsums[blockIdx.x] = s[t];
}

__global__ __launch_bounds__(128) void k_scan_top(int* __restrict__ bsums, int nb) {
    __shared__ int s[128];
    int t = threadIdx.x;
    int v = (t < nb) ? bsums[t] : 0;
    s[t] = v;
    __syncthreads();
    for (int d = 1; d < 128; d <<= 1) {
        int x = (t >= d) ? s[t - d] : 0;
        __syncthreads();
        s[t] += x;
        __syncthreads();
    }
    if (t < nb) bsums[t] = s[t] - v;
}

__global__ __launch_bounds__(1024) void k_scan_add(int* __restrict__ offs,
                                                   const int* __restrict__ bsums) {
    int i = blockIdx.x * 1024 + threadIdx.x;
    if (i < N_NODES) offs[i] += bsums[blockIdx.x];
}

// ---------------- dinv ----------------
__global__ void k_dinv(const int* __restrict__ deg, float* __restrict__ dinv) {
    int n = blockIdx.x * blockDim.x + threadIdx.x;
    if (n < N_NODES) {
        int d = deg[n];
        dinv[n] = (d > 0) ? rsqrtf((float)d) : 0.f;
    }
}

// ---------------- CSR fill, XCD-range-partitioned; row read only on match ----------------
__global__ __launch_bounds__(256) void k_fill(const int* __restrict__ row,
                                              const int* __restrict__ col,
                                              const int* __restrict__ offs,
                                              int* __restrict__ cursor,
                                              int* __restrict__ csr_src) {
    int range = blockIdx.x & (NRANGES - 1);
    int chunk = blockIdx.x >> 3;
    int lo = range * RANGE_SIZE;
    int hi = lo + RANGE_SIZE;
    int base = chunk * CHUNK_EDGES + threadIdx.x;
#pragma unroll
    for (int k = 0; k < CHUNK_EDGES / 256; ++k) {
        int e = base + k * 256;
        if (e < N_EDGES) {
            int c = col[e];
            if (c >= lo && c < hi) {
                int r = row[e];
                int p = atomicAdd(&cursor[c], 1);
                csr_src[offs[c] + p] = r;
            }
        }
    }
}

// ---------------- degree counting-sort: hist -> scan -> place ----------------
__global__ void k_hist(const int* __restrict__ deg, int* __restrict__ hist) {
    int n = blockIdx.x * blockDim.x + threadIdx.x;
    if (n < N_NODES) atomicAdd(&hist[min(deg[n], 255)], 1);
}

__global__ __launch_bounds__(256) void k_hscan(int* __restrict__ hist, int* __restrict__ cur) {
    __shared__ int s[256];
    int t = threadIdx.x;
    int v = hist[t];
    s[t] = v;
    __syncthreads();
    for (int d = 1; d < 256; d <<= 1) {
        int x = (t >= d) ? s[t - d] : 0;
        __syncthreads();
        s[t] += x;
        __syncthreads();
    }
    cur[t] = s[t] - v;
}

__global__ void k_place(const int* __restrict__ deg, int* __restrict__ cur,
                        int* __restrict__ sorted) {
    int n = blockIdx.x * blockDim.x + threadIdx.x;
    if (n < N_NODES) {
        int b = min(deg[n], 255);
        int p = atomicAdd(&cur[b], 1);
        sorted[p] = n;
    }
}

// ---------------- prescale x into 2 slice tables [2][N1][8] ----------------
__global__ void k_prex(const float* __restrict__ x, const float* __restrict__ dinv,
                       float* __restrict__ xsAB) {
    int i = blockIdx.x * blockDim.x + threadIdx.x;
    if (i >= N1 * 16) return;
    int n = i >> 4, d = i & 15;
    float v = 0.f;
    if (n < N_NODES && d < IN_DIM) v = x[n * IN_DIM + d] * dinv[n];
    xsAB[(size_t)(d >> 3) * SLICE + (size_t)n * 8 + (d & 7)] = v;
}

// ---------------- zero the gather-sink rows of the h slice table ----------------
__global__ void k_zerosink(float* __restrict__ hslc) {
    int t = threadIdx.x;  // 64
    hslc[(size_t)(t >> 3) * SLICE + (size_t)N_NODES * 8 + (t & 7)] = 0.f;
}

// ---------------- graph boundaries (batch is sorted) ----------------
__global__ void k_bounds(const int* __restrict__ batch, int* __restrict__ gmin,
                         int* __restrict__ gmax) {
    int n = blockIdx.x * blockDim.x + threadIdx.x;
    if (n < N_NODES) {
        int g = batch[n];
        atomicMin(&gmin[g], n);
        atomicMax(&gmax[g], n + 1);
    }
}

// ============ sliced gather, vectorized quad-wave ============
// grid = NPASS * QNB, pass-major. Slice table = [pass][N1][8] (3.2MB, L2-resident).
// Wave = 4 nodes; 16 lanes per node = 4 edge-subslots x 4 float2 columns.
// Per 16-edge chunk: one NT csr load, 4 independent float2 gathers per lane.
// deg-sorted -> the 4 nodes per wave have ~equal degree (balanced divergence).
__global__ __launch_bounds__(256, 3) void k_gslice(const float* __restrict__ tab0,
                                                   const int* __restrict__ offs,
                                                   const int* __restrict__ deg,
                                                   const int* __restrict__ csr,
                                                   const int* __restrict__ sorted,
                                                   float* __restrict__ out0) {
    int bip = blockIdx.x % QNB;
    int pass = blockIdx.x / QNB;
    const float* tab = tab0 + (size_t)pass * SLICE;
    float* outp = out0 + (size_t)pass * SLICE;

    // warm this block's 512B share of the slice (sequential fill -> streaming rate)
    if (threadIdx.x < 32) {
        f32x4 v = *((const f32x4*)(tab + (size_t)bip * 128) + threadIdx.x);
        float s = v.x + v.y + v.z + v.w;
        asm volatile("" :: "v"(s));  // keep loads live (no DCE)
    }

    int lane = threadIdx.x & 63;
    int g = lane >> 4;          // node within quad
    int f = lane & 15;          // lane within node group
    int e = f >> 2;             // edge subslot (0..3)
    int c = f & 3;              // float2 column (dims c*2, c*2+1)
    int gb = lane & 48;         // group base lane

    int quad = bip * 4 + (threadIdx.x >> 6);
    int n = sorted[quad * 4 + g];
    int start = offs[n], dn = deg[n];

    float ax = 0.f, ay = 0.f;
    for (int base = 0; base < dn; base += 16) {
        int sv = __builtin_nontemporal_load(&csr[start + base + f]);
        sv = (base + f < dn) ? sv : N_NODES;  // sink row = zeros
        int s0 = __shfl(sv, gb + 0 + e);
        int s1 = __shfl(sv, gb + 4 + e);
        int s2 = __shfl(sv, gb + 8 + e);
        int s3 = __shfl(sv, gb + 12 + e);
        float2 v0 = *(const float2*)&tab[(size_t)s0 * 8 + c * 2];
        float2 v1 = *(const float2*)&tab[(size_t)s1 * 8 + c * 2];
        float2 v2 = *(const float2*)&tab[(size_t)s2 * 8 + c * 2];
        float2 v3 = *(const float2*)&tab[(size_t)s3 * 8 + c * 2];
        ax += v0.x + v1.x + v2.x + v3.x;
        ay += v0.y + v1.y + v2.y + v3.y;
    }
    // reduce over the 4 edge subslots (stride 4 within the 16-lane group)
    ax += __shfl_xor(ax, 4); ay += __shfl_xor(ay, 4);
    ax += __shfl_xor(ax, 8); ay += __shfl_xor(ay, 8);
    if (e == 0) {
        float* dst = &outp[(size_t)n * 8 + c * 2];
        __builtin_nontemporal_store(ax, dst);
        __builtin_nontemporal_store(ay, dst + 1);
    }
}

// ============ dense 1: agg(16 padded dims) @ W1 + b1, relu, *dinv -> h1slc ============
__global__ __launch_bounds__(256) void k_dense1(const float* __restrict__ agg, // [2][N1][8]
                                                const float* __restrict__ dinv,
                                                const float* __restrict__ W1,
                                                const float* __restrict__ b1,
                                                float* __restrict__ h1slc) {  // [8][N1][8]
    int lane = threadIdx.x & 63;
    int f16 = lane & 15;
    float W1reg[16];
#pragma unroll
    for (int k = 0; k < 16; ++k) W1reg[k] = (k < IN_DIM) ? W1[k * HIDDEN + lane] : 0.f;
    float b1reg = b1[lane];
    size_t so = (size_t)(lane >> 3) * SLICE + (lane & 7);
    size_t ain = (size_t)(f16 >> 3) * SLICE + (f16 & 7);
    int wid = (blockIdx.x * 256 + threadIdx.x) >> 6;
    int nwaves = gridDim.x * 4;
    for (int quad = wid; quad < NQUADS; quad += nwaves) {
        int n = quad * 4 + (lane >> 4);
        float a = agg[ain + (size_t)n * 8] * dinv[n];
#pragma unroll
        for (int g = 0; g < 4; ++g) {
            float acc = b1reg;
#pragma unroll
            for (int k = 0; k < 16; ++k) acc += __shfl(a, g * 16 + k) * W1reg[k];
            int ng = quad * 4 + g;
            h1slc[so + (size_t)ng * 8] = fmaxf(acc, 0.f) * dinv[ng];
        }
    }
}

// ============ dense 2: agg(64) @ W + b, relu, *dinv -> out slice table ============
__global__ __launch_bounds__(256) void k_dense2(const float* __restrict__ agg, // [8][N1][8]
                                                const float* __restrict__ dinv,
                                                const float* __restrict__ W,
                                                const float* __restrict__ b,
                                                float* __restrict__ outslc) {  // [8][N1][8]
    __shared__ f32x4 sW4[HIDDEN][16];
    for (int i = threadIdx.x; i < HIDDEN * 16; i += 256) {
        int k = i >> 4, ff = i & 15;
        sW4[k][ff] = *(const f32x4*)&W[k * HIDDEN + ff * 4];
    }
    __syncthreads();
    int lane = threadIdx.x & 63;
    int f = lane & 15, gbase = lane & 48;
    f32x4 b4 = *(const f32x4*)&b[f * 4];
    size_t aoff = (size_t)(f >> 1) * SLICE + (f & 1) * 4;  // dims f*4..f*4+3
    int wid = (blockIdx.x * 256 + threadIdx.x) >> 6;
    int nwaves = gridDim.x * 4;
    for (int quad = wid; quad < NQUADS; quad += nwaves) {
        int n = quad * 4 + (lane >> 4);
        float di = dinv[n];
        f32x4 acc = *(const f32x4*)&agg[aoff + (size_t)n * 8];
        acc *= di;
        f32x4 out = b4;
#pragma unroll
        for (int k = 0; k < HIDDEN; ++k) {
            float srcv = (k & 3) == 0 ? acc.x : (k & 3) == 1 ? acc.y : (k & 3) == 2 ? acc.z : acc.w;
            float ak = __shfl(srcv, gbase + (k >> 2));
            f32x4 w4 = sW4[k][f];
            out += ak * w4;
        }
        out.x = fmaxf(out.x, 0.f) * di;
        out.y = fmaxf(out.y, 0.f) * di;
        out.z = fmaxf(out.z, 0.f) * di;
        out.w = fmaxf(out.w, 0.f) * di;
        *(f32x4*)&outslc[aoff + (size_t)n * 8] = out;
    }
}

// ============ pool: gpool[g][d] = sum_{n in [gmin,gmax)} agg[d-slice][n]*dinv[n] ============
__global__ __launch_bounds__(64) void k_pool(const float* __restrict__ agg, // [8][N1][8]
                                             const float* __restrict__ dinv,
                                             const int* __restrict__ gmin,
                                             const int* __restrict__ gmax,
                                             float* __restrict__ gpool,
                                             int* __restrict__ gcnt) {
    int g = blockIdx.x;
    int d = threadIdx.x;
    size_t off = (size_t)(d >> 3) * SLICE + (d & 7);
    int lo = gmin[g], hi = gmax[g];
    float s = 0.f;
    for (int n = lo; n < hi; ++n) s += agg[off + (size_t)n * 8] * dinv[n];
    gpool[g * HIDDEN + d] = s;
    if (d == 0) gcnt[g] = (hi > lo) ? (hi - lo) : 0;
}

// ---------------- final: pooled @ W3 + cnt*b3, @ Wl + bl, softmax ----------------
__global__ __launch_bounds__(256) void k_final(const float* __restrict__ gpool,
                                               const int* __restrict__ gcnt,
                                               const float* __restrict__ W3,
                                               const float* __restrict__ b3,
                                               const float* __restrict__ Wl,
                                               const float* __restrict__ bl,
                                               float* __restrict__ out) {
    int wid = (blockIdx.x * blockDim.x + threadIdx.x) >> 6;
    int lane = threadIdx.x & 63;
    if (wid >= N_GRAPHS) return;
    float pre = gpool[wid * HIDDEN + lane];
    float cnt = (float)gcnt[wid];
    float emb = cnt * b3[lane];
    for (int k = 0; k < HIDDEN; ++k) {
        emb += __shfl(pre, k) * W3[k * HIDDEN + lane];
    }
    float p0 = emb * Wl[lane * 2 + 0];
    float p1 = emb * Wl[lane * 2 + 1];
    for (int d = 32; d > 0; d >>= 1) {
        p0 += __shfl_xor(p0, d);
        p1 += __shfl_xor(p1, d);
    }
    if (lane == 0) {
        float l0 = p0 + bl[0], l1 = p1 + bl[1];
        float m = fmaxf(l0, l1);
        float e0 = __expf(l0 - m), e1 = __expf(l1 - m);
        float inv = 1.f / (e0 + e1);
        out[wid * 2 + 0] = e0 * inv;
        out[wid * 2 + 1] = e1 * inv;
    }
}

extern "C" void kernel_launch(void* const* d_in, const int* in_sizes, int n_in,
                              void* d_out, int out_size, void* d_ws, size_t ws_size,
                              hipStream_t stream) {
    const float* x = (const float*)d_in[0];
    const int* edge = (const int*)d_in[1];
    const int* batch = (const int*)d_in[2];
    const float* W1 = (const float*)d_in[3];
    const float* b1 = (const float*)d_in[4];
    const float* W2 = (const float*)d_in[5];
    const float* b2 = (const float*)d_in[6];
    const float* W3 = (const float*)d_in[7];
    const float* b3 = (const float*)d_in[8];
    const float* Wl = (const float*)d_in[9];
    const float* bl = (const float*)d_in[10];
    float* out = (float*)d_out;

    const int* row = edge;
    const int* col = edge + N_EDGES;

    char* ws = (char*)d_ws;
    size_t off = 0;
    auto alloc = [&](size_t bytes) -> void* {
        void* p = ws + off;
        off = (off + bytes + 255) & ~(size_t)255;
        return p;
    };
    int* deg = (int*)alloc((size_t)N_NODES * 4);
    int* offs = (int*)alloc((size_t)N_NODES * 4);
    int* bsums = (int*)alloc(128 * 4);
    int* cursor = (int*)alloc((size_t)N_NODES * 4);
    float* dinv = (float*)alloc((size_t)N_NODES * 4);
    int* sorted = (int*)alloc((size_t)N_NODES * 4);
    int* hist = (int*)alloc(256 * 4);
    int* bincur = (int*)alloc(256 * 4);
    int* csr_src = (int*)alloc(((size_t)N_EDGES + 1024) * 4);
    float* xsAB = (float*)alloc((size_t)2 * SLICE * 4);   // [2][N1][8]
    float* h1slc = (float*)alloc((size_t)8 * SLICE * 4);  // [8][N1][8]; h2 written in place
    float* aggA = (float*)alloc((size_t)8 * SLICE * 4);   // [8][N1][8]
    float* gpool = (float*)alloc((size_t)N_GRAPHS * HIDDEN * 4);
    int* gmin = (int*)alloc((size_t)N_GRAPHS * 4);
    int* gmax = (int*)alloc((size_t)N_GRAPHS * 4);
    int* gcnt = (int*)alloc((size_t)N_GRAPHS * 4);

    hipMemsetAsync(deg, 0, (size_t)N_NODES * 4, stream);
    hipMemsetAsync(cursor, 0, (size_t)N_NODES * 4, stream);
    hipMemsetAsync(hist, 0, 256 * 4, stream);
    hipMemsetAsync(gmin, 0x7f, (size_t)N_GRAPHS * 4, stream);
    hipMemsetAsync(gmax, 0, (size_t)N_GRAPHS * 4, stream);

    const int EB = (N_EDGES + 255) / 256;
    const int NB1024 = (N_NODES + 1023) / 1024;
    const int NB256 = (N_NODES + 255) / 256;

    k_deg<<<EB, 256, 0, stream>>>(col, deg);
    k_scan_block<<<NB1024, 1024, 0, stream>>>(deg, offs, bsums);
    k_scan_top<<<1, 128, 0, stream>>>(bsums, NB1024);
    k_scan_add<<<NB1024, 1024, 0, stream>>>(offs, bsums);
    k_dinv<<<NB256, 256, 0, stream>>>(deg, dinv);

    // degree counting-sort (balances quad-wave degrees)
    k_hist<<<NB256, 256, 0, stream>>>(deg, hist);
    k_hscan<<<1, 256, 0, stream>>>(hist, bincur);
    k_place<<<NB256, 256, 0, stream>>>(deg, bincur, sorted);

    const int NCHUNKS = (N_EDGES + CHUNK_EDGES - 1) / CHUNK_EDGES;
    k_fill<<<NCHUNKS * NRANGES, 256, 0, stream>>>(row, col, offs, cursor, csr_src);
    k_prex<<<(N1 * 16 + 255) / 256, 256, 0, stream>>>(x, dinv, xsAB);
    k_zerosink<<<1, 64, 0, stream>>>(h1slc);
    k_bounds<<<NB256, 256, 0, stream>>>(batch, gmin, gmax);

    // layer 1: 2 sliced gather passes over xs, then dense W1 -> h1slc
    k_gslice<<<2 * QNB, 256, 0, stream>>>(xsAB, offs, deg, csr_src, sorted, aggA);
    k_dense1<<<2048, 256, 0, stream>>>(aggA, dinv, W1, b1, h1slc);
    // layer 2: 8 sliced gather passes over h1, then dense W2 (h2 in place of h1)
    k_gslice<<<8 * QNB, 256, 0, stream>>>(h1slc, offs, deg, csr_src, sorted, aggA);
    k_dense2<<<2048, 256, 0, stream>>>(aggA, dinv, W2, b2, h1slc);
    // layer 3: 8 sliced gather passes over h2; pool without atomics (W3 commutes past pool)
    k_gslice<<<8 * QNB, 256, 0, stream>>>(h1slc, offs, deg, csr_src, sorted, aggA);
    k_pool<<<N_GRAPHS, 64, 0, stream>>>(aggA, dinv, gmin, gmax, gpool, gcnt);
    k_final<<<(N_GRAPHS * 64 + 255) / 256, 256, 0, stream>>>(gpool, gcnt, W3, b3, Wl, bl, out);
}

// Round 9
// 1222.021 us; speedup vs baseline: 1.1314x; 1.1314x over previous
//
#include <hip/hip_runtime.h>

#define N_NODES 100000
#define N1 (N_NODES + 1)
#define N_EDGES 3200000
#define N_GRAPHS 1000
#define IN_DIM 10
#define HIDDEN 64
#define NQUADS (N_NODES / 4)   // 25000 exact

#define NRANGES 8
#define RANGE_SIZE ((N_NODES + NRANGES - 1) / NRANGES)
#define CHUNK_EDGES 4096
#define LAYER_BLOCKS 2048

typedef float f32x4 __attribute__((ext_vector_type(4)));
typedef unsigned int u32;
typedef unsigned int u32x2 __attribute__((ext_vector_type(2)));

// bf16 helpers: RNE pack of 2 floats into one u32; unpack lo/hi
__device__ __forceinline__ u32 rne1(float a) {
    u32 u = __float_as_uint(a);
    return (u + 0x7fffu + ((u >> 16) & 1u)) >> 16;
}
__device__ __forceinline__ u32 rne_pack(float a, float b) {
    return rne1(a) | (rne1(b) << 16);
}
__device__ __forceinline__ float bf_lo(u32 w) { return __uint_as_float(w << 16); }
__device__ __forceinline__ float bf_hi(u32 w) { return __uint_as_float(w & 0xffff0000u); }

// ---------------- degree histogram ----------------
__global__ void k_deg(const int* __restrict__ col, int* __restrict__ deg) {
    int e = blockIdx.x * blockDim.x + threadIdx.x;
    if (e < N_EDGES) atomicAdd(&deg[col[e]], 1);
}

// ---------------- hierarchical exclusive scan (offsets) ----------------
__global__ __launch_bounds__(1024) void k_scan_block(const int* __restrict__ deg,
                                                     int* __restrict__ offs,
                                                     int* __restrict__ bsums) {
    __shared__ int s[1024];
    int t = threadIdx.x;
    int i = blockIdx.x * 1024 + t;
    int v = (i < N_NODES) ? deg[i] : 0;
    s[t] = v;
    __syncthreads();
    for (int d = 1; d < 1024; d <<= 1) {
        int x = (t >= d) ? s[t - d] : 0;
        __syncthreads();
        s[t] += x;
        __syncthreads();
    }
    if (i < N_NODES) offs[i] = s[t] - v;
    if (t == 1023) bsums[blockIdx.x] = s[t];
}

__global__ __launch_bounds__(128) void k_scan_top(int* __restrict__ bsums, int nb) {
    __shared__ int s[128];
    int t = threadIdx.x;
    int v = (t < nb) ? bsums[t] : 0;
    s[t] = v;
    __syncthreads();
    for (int d = 1; d < 128; d <<= 1) {
        int x = (t >= d) ? s[t - d] : 0;
        __syncthreads();
        s[t] += x;
        __syncthreads();
    }
    if (t < nb) bsums[t] = s[t] - v;
}

__global__ __launch_bounds__(1024) void k_scan_add(int* __restrict__ offs,
                                                   const int* __restrict__ bsums) {
    int i = blockIdx.x * 1024 + threadIdx.x;
    if (i < N_NODES) offs[i] += bsums[blockIdx.x];
}

// ---------------- dinv ----------------
__global__ void k_dinv(const int* __restrict__ deg, float* __restrict__ dinv) {
    int n = blockIdx.x * blockDim.x + threadIdx.x;
    if (n < N_NODES) {
        int d = deg[n];
        dinv[n] = (d > 0) ? rsqrtf((float)d) : 0.f;
    }
}

// ---------------- CSR fill, XCD-range-partitioned ----------------
__global__ __launch_bounds__(256) void k_fill(const int* __restrict__ row,
                                              const int* __restrict__ col,
                                              const int* __restrict__ offs,
                                              int* __restrict__ cursor,
                                              int* __restrict__ csr_src) {
    int range = blockIdx.x & (NRANGES - 1);
    int chunk = blockIdx.x >> 3;
    int lo = range * RANGE_SIZE;
    int hi = lo + RANGE_SIZE;
    int base = chunk * CHUNK_EDGES + threadIdx.x;
#pragma unroll
    for (int k = 0; k < CHUNK_EDGES / 256; ++k) {
        int e = base + k * 256;
        if (e < N_EDGES) {
            int c = col[e];
            if (c >= lo && c < hi) {
                int r = row[e];
                int p = atomicAdd(&cursor[c], 1);
                csr_src[offs[c] + p] = r;
            }
        }
    }
}

// ---------------- degree counting-sort: hist -> scan -> place ----------------
__global__ void k_hist(const int* __restrict__ deg, int* __restrict__ hist) {
    int n = blockIdx.x * blockDim.x + threadIdx.x;
    if (n < N_NODES) atomicAdd(&hist[min(deg[n], 255)], 1);
}

__global__ __launch_bounds__(256) void k_hscan(int* __restrict__ hist, int* __restrict__ cur) {
    __shared__ int s[256];
    int t = threadIdx.x;
    int v = hist[t];
    s[t] = v;
    __syncthreads();
    for (int d = 1; d < 256; d <<= 1) {
        int x = (t >= d) ? s[t - d] : 0;
        __syncthreads();
        s[t] += x;
        __syncthreads();
    }
    cur[t] = s[t] - v;
}

__global__ void k_place(const int* __restrict__ deg, int* __restrict__ cur,
                        int* __restrict__ sorted) {
    int n = blockIdx.x * blockDim.x + threadIdx.x;
    if (n < N_NODES) {
        int b = min(deg[n], 255);
        int p = atomicAdd(&cur[b], 1);
        sorted[p] = n;
    }
}

// ---------------- prescale x into padded 16-float rows [N1][16] (f32) ----------------
__global__ void k_prex(const float* __restrict__ x, const float* __restrict__ dinv,
                       float* __restrict__ xs) {
    int i = blockIdx.x * blockDim.x + threadIdx.x;
    if (i >= N1 * 16) return;
    int n = i >> 4, d = i & 15;
    float v = 0.f;
    if (n < N_NODES && d < IN_DIM) v = x[n * IN_DIM + d] * dinv[n];
    xs[i] = v;
}

// ---------------- graph boundaries (batch is sorted) ----------------
__global__ void k_bounds(const int* __restrict__ batch, int* __restrict__ gmin,
                         int* __restrict__ gmax) {
    int n = blockIdx.x * blockDim.x + threadIdx.x;
    if (n < N_NODES) {
        int g = batch[n];
        atomicMin(&gmin[g], n);
        atomicMax(&gmax[g], n + 1);
    }
}

// ================= layer 1: f32 16-dim row gather, fused dense, bf16 output =============
// houtb[n] = pack_bf16( relu((sum_src xs[src]) * dinv[n] @ W1 + b1) * dinv[n] )
__global__ __launch_bounds__(256) void k_conv16(const float* __restrict__ xs,
                                                const float* __restrict__ dinv,
                                                const int* __restrict__ offs,
                                                const int* __restrict__ deg,
                                                const int* __restrict__ csr,
                                                const int* __restrict__ sorted,
                                                const float* __restrict__ W1,
                                                const float* __restrict__ b1,
                                                u32* __restrict__ houtb) {
    __shared__ f32x4 sW1[16][16];
    {
        int i = threadIdx.x;  // 256 = 16*16 exactly
        int k = i >> 4, ff = i & 15;
        f32x4 z = {0.f, 0.f, 0.f, 0.f};
        sW1[k][ff] = (k < IN_DIM) ? *(const f32x4*)&W1[k * HIDDEN + ff * 4] : z;
    }
    __syncthreads();
    int lane = threadIdx.x & 63;
    int f = lane & 15;          // lane within 16-lane node group
    int gbase = lane & 48;      // group base lane
    int sub = (lane >> 2) & 3;  // edge subslot
    int c = lane & 3;           // float4 column in 16-dim row
    f32x4 b4 = *(const f32x4*)&b1[f * 4];

    int wid = (blockIdx.x * 256 + threadIdx.x) >> 6;
    int nwaves = gridDim.x * 4;
    for (int quad = wid; quad < NQUADS; quad += nwaves) {
        int n = sorted[quad * 4 + (lane >> 4)];
        int start = offs[n], dn = deg[n];
        float di = dinv[n];
        f32x4 acc = {0.f, 0.f, 0.f, 0.f};
        for (int base = 0; base < dn; base += 16) {
            int sv = __builtin_nontemporal_load(&csr[start + base + f]);
            sv = (base + f < dn) ? sv : N_NODES;  // sink row = zeros
            int sj0 = __shfl(sv, gbase + 0 + sub);
            int sj1 = __shfl(sv, gbase + 4 + sub);
            int sj2 = __shfl(sv, gbase + 8 + sub);
            int sj3 = __shfl(sv, gbase + 12 + sub);
            f32x4 v0 = *(const f32x4*)&xs[(size_t)sj0 * 16 + c * 4];
            f32x4 v1 = *(const f32x4*)&xs[(size_t)sj1 * 16 + c * 4];
            f32x4 v2 = *(const f32x4*)&xs[(size_t)sj2 * 16 + c * 4];
            f32x4 v3 = *(const f32x4*)&xs[(size_t)sj3 * 16 + c * 4];
            acc += v0 + v1 + v2 + v3;
        }
        // reduce over the 4 edge subslots (stride 4, 8 within group)
        f32x4 r;
        r.x = __shfl_xor(acc.x, 4); r.y = __shfl_xor(acc.y, 4);
        r.z = __shfl_xor(acc.z, 4); r.w = __shfl_xor(acc.w, 4);
        acc += r;
        r.x = __shfl_xor(acc.x, 8); r.y = __shfl_xor(acc.y, 8);
        r.z = __shfl_xor(acc.z, 8); r.w = __shfl_xor(acc.w, 8);
        acc += r;
        acc *= di;
        // dense: out dims f*4..f*4+3; a_k at lane gbase+(k>>2), component k&3
        f32x4 out = b4;
#pragma unroll
        for (int k = 0; k < 16; ++k) {
            float srcv = (k & 3) == 0 ? acc.x : (k & 3) == 1 ? acc.y : (k & 3) == 2 ? acc.z : acc.w;
            float ak = __shfl(srcv, gbase + (k >> 2));
            out += ak * sW1[k][f];
        }
        out.x = fmaxf(out.x, 0.f) * di;
        out.y = fmaxf(out.y, 0.f) * di;
        out.z = fmaxf(out.z, 0.f) * di;
        out.w = fmaxf(out.w, 0.f) * di;
        u32x2 pv;
        pv.x = rne_pack(out.x, out.y);
        pv.y = rne_pack(out.z, out.w);
        __builtin_nontemporal_store(pv, (u32x2*)&houtb[(size_t)n * 32 + f * 2]);
    }
}

// ================= wide conv, bf16 table: 128B rows, 16 lanes/node, 2 tx/edge ============
// DENSE=1: houtb[n] = pack_bf16(relu(agg*di @ W + b) * di)   (layer 2)
// DENSE=0: aggf[n]  = agg*di  (f32, layer 3 pre-pool)
template <int DENSE>
__global__ __launch_bounds__(256, 4) void k_conv64b(const u32* __restrict__ tab,  // [N1][32]
                                                    const float* __restrict__ dinv,
                                                    const int* __restrict__ offs,
                                                    const int* __restrict__ deg,
                                                    const int* __restrict__ csr,
                                                    const int* __restrict__ sorted,
                                                    const float* __restrict__ W,
                                                    const float* __restrict__ b,
                                                    u32* __restrict__ houtb,
                                                    float* __restrict__ aggf) {
    __shared__ f32x4 sW4[HIDDEN][16];
    if (DENSE) {
        for (int i = threadIdx.x; i < HIDDEN * 16; i += 256) {
            int k = i >> 4, ff = i & 15;
            sW4[k][ff] = *(const f32x4*)&W[k * HIDDEN + ff * 4];
        }
        __syncthreads();
    }
    int lane = threadIdx.x & 63;
    int f = lane & 15;
    int gbase = lane & 48;
    f32x4 b4 = {0.f, 0.f, 0.f, 0.f};
    if (DENSE) b4 = *(const f32x4*)&b[f * 4];

    int wid = (blockIdx.x * 256 + threadIdx.x) >> 6;
    int nwaves = gridDim.x * 4;
    for (int quad = wid; quad < NQUADS; quad += nwaves) {
        int n = sorted[quad * 4 + (lane >> 4)];
        int start = offs[n], dn = deg[n];
        float di = dinv[n];
        f32x4 acc = {0.f, 0.f, 0.f, 0.f};
        for (int base = 0; base < dn; base += 16) {
            int sv = __builtin_nontemporal_load(&csr[start + base + f]);
            sv = (base + f < dn) ? sv : N_NODES;  // sink row = zeros
#pragma unroll
            for (int jj = 0; jj < 2; ++jj) {
                u32x2 v[8];
#pragma unroll
                for (int j = 0; j < 8; ++j) {
                    int sj = __shfl(sv, gbase + jj * 8 + j);
                    v[j] = *(const u32x2*)&tab[(size_t)sj * 32 + f * 2];
                }
#pragma unroll
                for (int j = 0; j < 8; ++j) {
                    acc.x += bf_lo(v[j].x);
                    acc.y += bf_hi(v[j].x);
                    acc.z += bf_lo(v[j].y);
                    acc.w += bf_hi(v[j].y);
                }
            }
        }
        acc *= di;
        if (DENSE) {
            f32x4 out = b4;
#pragma unroll
            for (int k = 0; k < HIDDEN; ++k) {
                float srcv = (k & 3) == 0 ? acc.x : (k & 3) == 1 ? acc.y : (k & 3) == 2 ? acc.z : acc.w;
                float ak = __shfl(srcv, gbase + (k >> 2));
                out += ak * sW4[k][f];
            }
            out.x = fmaxf(out.x, 0.f) * di;
            out.y = fmaxf(out.y, 0.f) * di;
            out.z = fmaxf(out.z, 0.f) * di;
            out.w = fmaxf(out.w, 0.f) * di;
            u32x2 pv;
            pv.x = rne_pack(out.x, out.y);
            pv.y = rne_pack(out.z, out.w);
            __builtin_nontemporal_store(pv, (u32x2*)&houtb[(size_t)n * 32 + f * 2]);
        } else {
            __builtin_nontemporal_store(acc, (f32x4*)&aggf[(size_t)n * HIDDEN + f * 4]);
        }
    }
}

// ================= pool: gpool[g][d] = sum_{n in [gmin,gmax)} agg[n][d]; no atomics ========
__global__ __launch_bounds__(64) void k_pool(const float* __restrict__ agg,
                                             const int* __restrict__ gmin,
                                             const int* __restrict__ gmax,
                                             float* __restrict__ gpool,
                                             int* __restrict__ gcnt) {
    int g = blockIdx.x;
    int d = threadIdx.x;
    int lo = gmin[g], hi = gmax[g];
    float s = 0.f;
    for (int n = lo; n < hi; ++n) s += agg[(size_t)n * HIDDEN + d];
    gpool[g * HIDDEN + d] = s;
    if (d == 0) gcnt[g] = (hi > lo) ? (hi - lo) : 0;
}

// ---------------- final: pooled @ W3 + cnt*b3, @ Wl + bl, softmax ----------------
__global__ __launch_bounds__(256) void k_final(const float* __restrict__ gpool,
                                               const int* __restrict__ gcnt,
                                               const float* __restrict__ W3,
                                               const float* __restrict__ b3,
                                               const float* __restrict__ Wl,
                                               const float* __restrict__ bl,
                                               float* __restrict__ out) {
    int wid = (blockIdx.x * blockDim.x + threadIdx.x) >> 6;
    int lane = threadIdx.x & 63;
    if (wid >= N_GRAPHS) return;
    float pre = gpool[wid * HIDDEN + lane];
    float cnt = (float)gcnt[wid];
    float emb = cnt * b3[lane];
    for (int k = 0; k < HIDDEN; ++k) {
        emb += __shfl(pre, k) * W3[k * HIDDEN + lane];
    }
    float p0 = emb * Wl[lane * 2 + 0];
    float p1 = emb * Wl[lane * 2 + 1];
    for (int d = 32; d > 0; d >>= 1) {
        p0 += __shfl_xor(p0, d);
        p1 += __shfl_xor(p1, d);
    }
    if (lane == 0) {
        float l0 = p0 + bl[0], l1 = p1 + bl[1];
        float m = fmaxf(l0, l1);
        float e0 = __expf(l0 - m), e1 = __expf(l1 - m);
        float inv = 1.f / (e0 + e1);
        out[wid * 2 + 0] = e0 * inv;
        out[wid * 2 + 1] = e1 * inv;
    }
}

extern "C" void kernel_launch(void* const* d_in, const int* in_sizes, int n_in,
                              void* d_out, int out_size, void* d_ws, size_t ws_size,
                              hipStream_t stream) {
    const float* x = (const float*)d_in[0];
    const int* edge = (const int*)d_in[1];
    const int* batch = (const int*)d_in[2];
    const float* W1 = (const float*)d_in[3];
    const float* b1 = (const float*)d_in[4];
    const float* W2 = (const float*)d_in[5];
    const float* b2 = (const float*)d_in[6];
    const float* W3 = (const float*)d_in[7];
    const float* b3 = (const float*)d_in[8];
    const float* Wl = (const float*)d_in[9];
    const float* bl = (const float*)d_in[10];
    float* out = (float*)d_out;

    const int* row = edge;
    const int* col = edge + N_EDGES;

    char* ws = (char*)d_ws;
    size_t off = 0;
    auto alloc = [&](size_t bytes) -> void* {
        void* p = ws + off;
        off = (off + bytes + 255) & ~(size_t)255;
        return p;
    };
    int* deg = (int*)alloc((size_t)N_NODES * 4);
    int* offs = (int*)alloc((size_t)N_NODES * 4);
    int* bsums = (int*)alloc(128 * 4);
    int* cursor = (int*)alloc((size_t)N_NODES * 4);
    float* dinv = (float*)alloc((size_t)N_NODES * 4);
    int* sorted = (int*)alloc((size_t)N_NODES * 4);
    int* hist = (int*)alloc(256 * 4);
    int* bincur = (int*)alloc(256 * 4);
    int* csr_src = (int*)alloc(((size_t)N_EDGES + 1024) * 4);
    float* xs = (float*)alloc((size_t)N1 * 16 * 4);       // [N1][16] f32, x*dinv, padded
    u32* h1b = (u32*)alloc((size_t)N1 * 32 * 4);          // [N1][32] packed bf16 (64 dims)
    u32* h2b = (u32*)alloc((size_t)N1 * 32 * 4);          // [N1][32] packed bf16
    float* agg3 = (float*)alloc((size_t)N1 * HIDDEN * 4); // [N1][64] f32 pre-pool
    float* gpool = (float*)alloc((size_t)N_GRAPHS * HIDDEN * 4);
    int* gmin = (int*)alloc((size_t)N_GRAPHS * 4);
    int* gmax = (int*)alloc((size_t)N_GRAPHS * 4);
    int* gcnt = (int*)alloc((size_t)N_GRAPHS * 4);

    (void)hipMemsetAsync(deg, 0, (size_t)N_NODES * 4, stream);
    (void)hipMemsetAsync(cursor, 0, (size_t)N_NODES * 4, stream);
    (void)hipMemsetAsync(hist, 0, 256 * 4, stream);
    (void)hipMemsetAsync(gmin, 0x7f, (size_t)N_GRAPHS * 4, stream);
    (void)hipMemsetAsync(gmax, 0, (size_t)N_GRAPHS * 4, stream);
    // zero the gather-sink rows (row N_NODES)
    (void)hipMemsetAsync(h1b + (size_t)N_NODES * 32, 0, 32 * 4, stream);
    (void)hipMemsetAsync(h2b + (size_t)N_NODES * 32, 0, 32 * 4, stream);

    const int EB = (N_EDGES + 255) / 256;
    const int NB1024 = (N_NODES + 1023) / 1024;
    const int NB256 = (N_NODES + 255) / 256;

    k_deg<<<EB, 256, 0, stream>>>(col, deg);
    k_scan_block<<<NB1024, 1024, 0, stream>>>(deg, offs, bsums);
    k_scan_top<<<1, 128, 0, stream>>>(bsums, NB1024);
    k_scan_add<<<NB1024, 1024, 0, stream>>>(offs, bsums);
    k_dinv<<<NB256, 256, 0, stream>>>(deg, dinv);

    // degree counting-sort (balances quad-wave degrees)
    k_hist<<<NB256, 256, 0, stream>>>(deg, hist);
    k_hscan<<<1, 256, 0, stream>>>(hist, bincur);
    k_place<<<NB256, 256, 0, stream>>>(deg, bincur, sorted);

    const int NCHUNKS = (N_EDGES + CHUNK_EDGES - 1) / CHUNK_EDGES;
    k_fill<<<NCHUNKS * NRANGES, 256, 0, stream>>>(row, col, offs, cursor, csr_src);
    k_prex<<<(N1 * 16 + 255) / 256, 256, 0, stream>>>(x, dinv, xs);
    k_bounds<<<NB256, 256, 0, stream>>>(batch, gmin, gmax);

    k_conv16<<<LAYER_BLOCKS, 256, 0, stream>>>(xs, dinv, offs, deg, csr_src, sorted, W1, b1, h1b);
    k_conv64b<1><<<LAYER_BLOCKS, 256, 0, stream>>>(h1b, dinv, offs, deg, csr_src, sorted, W2, b2,
                                                   h2b, (float*)nullptr);
    k_conv64b<0><<<LAYER_BLOCKS, 256, 0, stream>>>(h2b, dinv, offs, deg, csr_src, sorted, W2, b2,
                                                   (u32*)nullptr, agg3);
    k_pool<<<N_GRAPHS, 64, 0, stream>>>(agg3, gmin, gmax, gpool, gcnt);
    k_final<<<(N_GRAPHS * 64 + 255) / 256, 256, 0, stream>>>(gpool, gcnt, W3, b3, Wl, bl, out);
}

// Round 10
// 1058.377 us; speedup vs baseline: 1.3063x; 1.1546x over previous
//
#include <hip/hip_runtime.h>

#define N_NODES 100000
#define N1 (N_NODES + 1)
#define N_EDGES 3200000
#define N_GRAPHS 1000
#define IN_DIM 10
#define HIDDEN 64
#define NQUADS (N_NODES / 4)   // 25000 exact

#define NRANGES 8
#define RANGE_SIZE ((N_NODES + NRANGES - 1) / NRANGES)
#define CHUNK_EDGES 4096
#define LAYER_BLOCKS 2048

typedef float f32x4 __attribute__((ext_vector_type(4)));
typedef unsigned int u32;
typedef unsigned int u32x2 __attribute__((ext_vector_type(2)));

// bf16 helpers: RNE pack of 2 floats into one u32; unpack lo/hi
__device__ __forceinline__ u32 rne1(float a) {
    u32 u = __float_as_uint(a);
    return (u + 0x7fffu + ((u >> 16) & 1u)) >> 16;
}
__device__ __forceinline__ u32 rne_pack(float a, float b) {
    return rne1(a) | (rne1(b) << 16);
}
__device__ __forceinline__ float bf_lo(u32 w) { return __uint_as_float(w << 16); }
__device__ __forceinline__ float bf_hi(u32 w) { return __uint_as_float(w & 0xffff0000u); }

// ---------------- degree histogram ----------------
__global__ void k_deg(const int* __restrict__ col, int* __restrict__ deg) {
    int e = blockIdx.x * blockDim.x + threadIdx.x;
    if (e < N_EDGES) atomicAdd(&deg[col[e]], 1);
}

// ---------------- hierarchical exclusive scan (offsets) ----------------
__global__ __launch_bounds__(1024) void k_scan_block(const int* __restrict__ deg,
                                                     int* __restrict__ offs,
                                                     int* __restrict__ bsums) {
    __shared__ int s[1024];
    int t = threadIdx.x;
    int i = blockIdx.x * 1024 + t;
    int v = (i < N_NODES) ? deg[i] : 0;
    s[t] = v;
    __syncthreads();
    for (int d = 1; d < 1024; d <<= 1) {
        int x = (t >= d) ? s[t - d] : 0;
        __syncthreads();
        s[t] += x;
        __syncthreads();
    }
    if (i < N_NODES) offs[i] = s[t] - v;
    if (t == 1023) bsums[blockIdx.x] = s[t];
}

__global__ __launch_bounds__(128) void k_scan_top(int* __restrict__ bsums, int nb) {
    __shared__ int s[128];
    int t = threadIdx.x;
    int v = (t < nb) ? bsums[t] : 0;
    s[t] = v;
    __syncthreads();
    for (int d = 1; d < 128; d <<= 1) {
        int x = (t >= d) ? s[t - d] : 0;
        __syncthreads();
        s[t] += x;
        __syncthreads();
    }
    if (t < nb) bsums[t] = s[t] - v;
}

__global__ __launch_bounds__(1024) void k_scan_add(int* __restrict__ offs,
                                                   const int* __restrict__ bsums) {
    int i = blockIdx.x * 1024 + threadIdx.x;
    if (i < N_NODES) offs[i] += bsums[blockIdx.x];
}

// ---------------- dinv ----------------
__global__ void k_dinv(const int* __restrict__ deg, float* __restrict__ dinv) {
    int n = blockIdx.x * blockDim.x + threadIdx.x;
    if (n < N_NODES) {
        int d = deg[n];
        dinv[n] = (d > 0) ? rsqrtf((float)d) : 0.f;
    }
}

// ---------------- CSR fill, XCD-range-partitioned ----------------
__global__ __launch_bounds__(256) void k_fill(const int* __restrict__ row,
                                              const int* __restrict__ col,
                                              const int* __restrict__ offs,
                                              int* __restrict__ cursor,
                                              int* __restrict__ csr_src) {
    int range = blockIdx.x & (NRANGES - 1);
    int chunk = blockIdx.x >> 3;
    int lo = range * RANGE_SIZE;
    int hi = lo + RANGE_SIZE;
    int base = chunk * CHUNK_EDGES + threadIdx.x;
#pragma unroll
    for (int k = 0; k < CHUNK_EDGES / 256; ++k) {
        int e = base + k * 256;
        if (e < N_EDGES) {
            int c = col[e];
            if (c >= lo && c < hi) {
                int r = row[e];
                int p = atomicAdd(&cursor[c], 1);
                csr_src[offs[c] + p] = r;
            }
        }
    }
}

// ---------------- degree counting-sort: hist -> scan -> place ----------------
__global__ void k_hist(const int* __restrict__ deg, int* __restrict__ hist) {
    int n = blockIdx.x * blockDim.x + threadIdx.x;
    if (n < N_NODES) atomicAdd(&hist[min(deg[n], 255)], 1);
}

__global__ __launch_bounds__(256) void k_hscan(int* __restrict__ hist, int* __restrict__ cur) {
    __shared__ int s[256];
    int t = threadIdx.x;
    int v = hist[t];
    s[t] = v;
    __syncthreads();
    for (int d = 1; d < 256; d <<= 1) {
        int x = (t >= d) ? s[t - d] : 0;
        __syncthreads();
        s[t] += x;
        __syncthreads();
    }
    cur[t] = s[t] - v;
}

__global__ void k_place(const int* __restrict__ deg, int* __restrict__ cur,
                        int* __restrict__ sorted) {
    int n = blockIdx.x * blockDim.x + threadIdx.x;
    if (n < N_NODES) {
        int b = min(deg[n], 255);
        int p = atomicAdd(&cur[b], 1);
        sorted[p] = n;
    }
}

// ---------------- prescale x into padded 16-float rows [N1][16] (f32) ----------------
__global__ void k_prex(const float* __restrict__ x, const float* __restrict__ dinv,
                       float* __restrict__ xs) {
    int i = blockIdx.x * blockDim.x + threadIdx.x;
    if (i >= N1 * 16) return;
    int n = i >> 4, d = i & 15;
    float v = 0.f;
    if (n < N_NODES && d < IN_DIM) v = x[n * IN_DIM + d] * dinv[n];
    xs[i] = v;
}

// ---------------- graph boundaries (batch is sorted) ----------------
__global__ void k_bounds(const int* __restrict__ batch, int* __restrict__ gmin,
                         int* __restrict__ gmax) {
    int n = blockIdx.x * blockDim.x + threadIdx.x;
    if (n < N_NODES) {
        int g = batch[n];
        atomicMin(&gmin[g], n);
        atomicMax(&gmax[g], n + 1);
    }
}

// ================= layer 1: f32 16-dim row gather, fused dense, bf16 output =============
// houtb[n] = pack_bf16( relu((sum_src xs[src]) * dinv[n] @ W1 + b1) * dinv[n] )
__global__ __launch_bounds__(256) void k_conv16(const float* __restrict__ xs,
                                                const float* __restrict__ dinv,
                                                const int* __restrict__ offs,
                                                const int* __restrict__ deg,
                                                const int* __restrict__ csr,
                                                const int* __restrict__ sorted,
                                                const float* __restrict__ W1,
                                                const float* __restrict__ b1,
                                                u32* __restrict__ houtb) {
    __shared__ f32x4 sW1[16][16];
    {
        int i = threadIdx.x;  // 256 = 16*16 exactly
        int k = i >> 4, ff = i & 15;
        f32x4 z = {0.f, 0.f, 0.f, 0.f};
        sW1[k][ff] = (k < IN_DIM) ? *(const f32x4*)&W1[k * HIDDEN + ff * 4] : z;
    }
    __syncthreads();
    int lane = threadIdx.x & 63;
    int f = lane & 15;          // lane within 16-lane node group
    int gbase = lane & 48;      // group base lane
    int sub = (lane >> 2) & 3;  // edge subslot
    int c = lane & 3;           // float4 column in 16-dim row
    f32x4 b4 = *(const f32x4*)&b1[f * 4];

    int wid = (blockIdx.x * 256 + threadIdx.x) >> 6;
    int nwaves = gridDim.x * 4;
    for (int quad = wid; quad < NQUADS; quad += nwaves) {
        int n = sorted[quad * 4 + (lane >> 4)];
        int start = offs[n], dn = deg[n];
        float di = dinv[n];
        f32x4 acc = {0.f, 0.f, 0.f, 0.f};
        for (int base = 0; base < dn; base += 16) {
            int sv = __builtin_nontemporal_load(&csr[start + base + f]);
            sv = (base + f < dn) ? sv : N_NODES;  // sink row = zeros
            int sj0 = __shfl(sv, gbase + 0 + sub);
            int sj1 = __shfl(sv, gbase + 4 + sub);
            int sj2 = __shfl(sv, gbase + 8 + sub);
            int sj3 = __shfl(sv, gbase + 12 + sub);
            f32x4 v0 = *(const f32x4*)&xs[(size_t)sj0 * 16 + c * 4];
            f32x4 v1 = *(const f32x4*)&xs[(size_t)sj1 * 16 + c * 4];
            f32x4 v2 = *(const f32x4*)&xs[(size_t)sj2 * 16 + c * 4];
            f32x4 v3 = *(const f32x4*)&xs[(size_t)sj3 * 16 + c * 4];
            acc += v0 + v1 + v2 + v3;
        }
        // reduce over the 4 edge subslots (stride 4, 8 within group)
        f32x4 r;
        r.x = __shfl_xor(acc.x, 4); r.y = __shfl_xor(acc.y, 4);
        r.z = __shfl_xor(acc.z, 4); r.w = __shfl_xor(acc.w, 4);
        acc += r;
        r.x = __shfl_xor(acc.x, 8); r.y = __shfl_xor(acc.y, 8);
        r.z = __shfl_xor(acc.z, 8); r.w = __shfl_xor(acc.w, 8);
        acc += r;
        acc *= di;
        // dense: out dims f*4..f*4+3; a_k at lane gbase+(k>>2), component k&3
        f32x4 out = b4;
#pragma unroll
        for (int k = 0; k < 16; ++k) {
            float srcv = (k & 3) == 0 ? acc.x : (k & 3) == 1 ? acc.y : (k & 3) == 2 ? acc.z : acc.w;
            float ak = __shfl(srcv, gbase + (k >> 2));
            out += ak * sW1[k][f];
        }
        out.x = fmaxf(out.x, 0.f) * di;
        out.y = fmaxf(out.y, 0.f) * di;
        out.z = fmaxf(out.z, 0.f) * di;
        out.w = fmaxf(out.w, 0.f) * di;
        u32x2 pv;
        pv.x = rne_pack(out.x, out.y);
        pv.y = rne_pack(out.z, out.w);
        __builtin_nontemporal_store(pv, (u32x2*)&houtb[(size_t)n * 32 + f * 2]);
    }
}

// ================= wide conv, bf16 table: 128B rows, 16 lanes/node, 2 tx/edge ============
// DENSE=1: houtb[n] = pack_bf16(relu(agg*di @ W + b) * di)   (layer 2)
// DENSE=0: aggf[n]  = agg*di  (f32, layer 3 pre-pool)
// NOTE: min-waves=2 (256-VGPR cap). (256,4) capped VGPRs at 64 and spilled the
// gather loop to scratch: WRITE_SIZE 408MB, FETCH +450MB, 1.8x slower (R9).
template <int DENSE>
__global__ __launch_bounds__(256, 2) void k_conv64b(const u32* __restrict__ tab,  // [N1][32]
                                                    const float* __restrict__ dinv,
                                                    const int* __restrict__ offs,
                                                    const int* __restrict__ deg,
                                                    const int* __restrict__ csr,
                                                    const int* __restrict__ sorted,
                                                    const float* __restrict__ W,
                                                    const float* __restrict__ b,
                                                    u32* __restrict__ houtb,
                                                    float* __restrict__ aggf) {
    __shared__ f32x4 sW4[HIDDEN][16];
    if (DENSE) {
        for (int i = threadIdx.x; i < HIDDEN * 16; i += 256) {
            int k = i >> 4, ff = i & 15;
            sW4[k][ff] = *(const f32x4*)&W[k * HIDDEN + ff * 4];
        }
        __syncthreads();
    }
    int lane = threadIdx.x & 63;
    int f = lane & 15;
    int gbase = lane & 48;
    f32x4 b4 = {0.f, 0.f, 0.f, 0.f};
    if (DENSE) b4 = *(const f32x4*)&b[f * 4];

    int wid = (blockIdx.x * 256 + threadIdx.x) >> 6;
    int nwaves = gridDim.x * 4;
    for (int quad = wid; quad < NQUADS; quad += nwaves) {
        int n = sorted[quad * 4 + (lane >> 4)];
        int start = offs[n], dn = deg[n];
        float di = dinv[n];
        f32x4 acc = {0.f, 0.f, 0.f, 0.f};
        for (int base = 0; base < dn; base += 16) {
            int sv = __builtin_nontemporal_load(&csr[start + base + f]);
            sv = (base + f < dn) ? sv : N_NODES;  // sink row = zeros
#pragma unroll
            for (int jj = 0; jj < 2; ++jj) {
                u32x2 v[8];
#pragma unroll
                for (int j = 0; j < 8; ++j) {
                    int sj = __shfl(sv, gbase + jj * 8 + j);
                    v[j] = *(const u32x2*)&tab[(size_t)sj * 32 + f * 2];
                }
#pragma unroll
                for (int j = 0; j < 8; ++j) {
                    acc.x += bf_lo(v[j].x);
                    acc.y += bf_hi(v[j].x);
                    acc.z += bf_lo(v[j].y);
                    acc.w += bf_hi(v[j].y);
                }
            }
        }
        acc *= di;
        if (DENSE) {
            f32x4 out = b4;
#pragma unroll
            for (int k = 0; k < HIDDEN; ++k) {
                float srcv = (k & 3) == 0 ? acc.x : (k & 3) == 1 ? acc.y : (k & 3) == 2 ? acc.z : acc.w;
                float ak = __shfl(srcv, gbase + (k >> 2));
                out += ak * sW4[k][f];
            }
            out.x = fmaxf(out.x, 0.f) * di;
            out.y = fmaxf(out.y, 0.f) * di;
            out.z = fmaxf(out.z, 0.f) * di;
            out.w = fmaxf(out.w, 0.f) * di;
            u32x2 pv;
            pv.x = rne_pack(out.x, out.y);
            pv.y = rne_pack(out.z, out.w);
            __builtin_nontemporal_store(pv, (u32x2*)&houtb[(size_t)n * 32 + f * 2]);
        } else {
            __builtin_nontemporal_store(acc, (f32x4*)&aggf[(size_t)n * HIDDEN + f * 4]);
        }
    }
}

// ================= pool: gpool[g][d] = sum_{n in [gmin,gmax)} agg[n][d]; no atomics ========
__global__ __launch_bounds__(64) void k_pool(const float* __restrict__ agg,
                                             const int* __restrict__ gmin,
                                             const int* __restrict__ gmax,
                                             float* __restrict__ gpool,
                                             int* __restrict__ gcnt) {
    int g = blockIdx.x;
    int d = threadIdx.x;
    int lo = gmin[g], hi = gmax[g];
    float s = 0.f;
    for (int n = lo; n < hi; ++n) s += agg[(size_t)n * HIDDEN + d];
    gpool[g * HIDDEN + d] = s;
    if (d == 0) gcnt[g] = (hi > lo) ? (hi - lo) : 0;
}

// ---------------- final: pooled @ W3 + cnt*b3, @ Wl + bl, softmax ----------------
__global__ __launch_bounds__(256) void k_final(const float* __restrict__ gpool,
                                               const int* __restrict__ gcnt,
                                               const float* __restrict__ W3,
                                               const float* __restrict__ b3,
                                               const float* __restrict__ Wl,
                                               const float* __restrict__ bl,
                                               float* __restrict__ out) {
    int wid = (blockIdx.x * blockDim.x + threadIdx.x) >> 6;
    int lane = threadIdx.x & 63;
    if (wid >= N_GRAPHS) return;
    float pre = gpool[wid * HIDDEN + lane];
    float cnt = (float)gcnt[wid];
    float emb = cnt * b3[lane];
    for (int k = 0; k < HIDDEN; ++k) {
        emb += __shfl(pre, k) * W3[k * HIDDEN + lane];
    }
    float p0 = emb * Wl[lane * 2 + 0];
    float p1 = emb * Wl[lane * 2 + 1];
    for (int d = 32; d > 0; d >>= 1) {
        p0 += __shfl_xor(p0, d);
        p1 += __shfl_xor(p1, d);
    }
    if (lane == 0) {
        float l0 = p0 + bl[0], l1 = p1 + bl[1];
        float m = fmaxf(l0, l1);
        float e0 = __expf(l0 - m), e1 = __expf(l1 - m);
        float inv = 1.f / (e0 + e1);
        out[wid * 2 + 0] = e0 * inv;
        out[wid * 2 + 1] = e1 * inv;
    }
}

extern "C" void kernel_launch(void* const* d_in, const int* in_sizes, int n_in,
                              void* d_out, int out_size, void* d_ws, size_t ws_size,
                              hipStream_t stream) {
    const float* x = (const float*)d_in[0];
    const int* edge = (const int*)d_in[1];
    const int* batch = (const int*)d_in[2];
    const float* W1 = (const float*)d_in[3];
    const float* b1 = (const float*)d_in[4];
    const float* W2 = (const float*)d_in[5];
    const float* b2 = (const float*)d_in[6];
    const float* W3 = (const float*)d_in[7];
    const float* b3 = (const float*)d_in[8];
    const float* Wl = (const float*)d_in[9];
    const float* bl = (const float*)d_in[10];
    float* out = (float*)d_out;

    const int* row = edge;
    const int* col = edge + N_EDGES;

    char* ws = (char*)d_ws;
    size_t off = 0;
    auto alloc = [&](size_t bytes) -> void* {
        void* p = ws + off;
        off = (off + bytes + 255) & ~(size_t)255;
        return p;
    };
    int* deg = (int*)alloc((size_t)N_NODES * 4);
    int* offs = (int*)alloc((size_t)N_NODES * 4);
    int* bsums = (int*)alloc(128 * 4);
    int* cursor = (int*)alloc((size_t)N_NODES * 4);
    float* dinv = (float*)alloc((size_t)N_NODES * 4);
    int* sorted = (int*)alloc((size_t)N_NODES * 4);
    int* hist = (int*)alloc(256 * 4);
    int* bincur = (int*)alloc(256 * 4);
    int* csr_src = (int*)alloc(((size_t)N_EDGES + 1024) * 4);
    float* xs = (float*)alloc((size_t)N1 * 16 * 4);       // [N1][16] f32, x*dinv, padded
    u32* h1b = (u32*)alloc((size_t)N1 * 32 * 4);          // [N1][32] packed bf16 (64 dims)
    u32* h2b = (u32*)alloc((size_t)N1 * 32 * 4);          // [N1][32] packed bf16
    float* agg3 = (float*)alloc((size_t)N1 * HIDDEN * 4); // [N1][64] f32 pre-pool
    float* gpool = (float*)alloc((size_t)N_GRAPHS * HIDDEN * 4);
    int* gmin = (int*)alloc((size_t)N_GRAPHS * 4);
    int* gmax = (int*)alloc((size_t)N_GRAPHS * 4);
    int* gcnt = (int*)alloc((size_t)N_GRAPHS * 4);

    (void)hipMemsetAsync(deg, 0, (size_t)N_NODES * 4, stream);
    (void)hipMemsetAsync(cursor, 0, (size_t)N_NODES * 4, stream);
    (void)hipMemsetAsync(hist, 0, 256 * 4, stream);
    (void)hipMemsetAsync(gmin, 0x7f, (size_t)N_GRAPHS * 4, stream);
    (void)hipMemsetAsync(gmax, 0, (size_t)N_GRAPHS * 4, stream);
    // zero the gather-sink rows (row N_NODES)
    (void)hipMemsetAsync(h1b + (size_t)N_NODES * 32, 0, 32 * 4, stream);
    (void)hipMemsetAsync(h2b + (size_t)N_NODES * 32, 0, 32 * 4, stream);

    const int EB = (N_EDGES + 255) / 256;
    const int NB1024 = (N_NODES + 1023) / 1024;
    const int NB256 = (N_NODES + 255) / 256;

    k_deg<<<EB, 256, 0, stream>>>(col, deg);
    k_scan_block<<<NB1024, 1024, 0, stream>>>(deg, offs, bsums);
    k_scan_top<<<1, 128, 0, stream>>>(bsums, NB1024);
    k_scan_add<<<NB1024, 1024, 0, stream>>>(offs, bsums);
    k_dinv<<<NB256, 256, 0, stream>>>(deg, dinv);

    // degree counting-sort (balances quad-wave degrees)
    k_hist<<<NB256, 256, 0, stream>>>(deg, hist);
    k_hscan<<<1, 256, 0, stream>>>(hist, bincur);
    k_place<<<NB256, 256, 0, stream>>>(deg, bincur, sorted);

    const int NCHUNKS = (N_EDGES + CHUNK_EDGES - 1) / CHUNK_EDGES;
    k_fill<<<NCHUNKS * NRANGES, 256, 0, stream>>>(row, col, offs, cursor, csr_src);
    k_prex<<<(N1 * 16 + 255) / 256, 256, 0, stream>>>(x, dinv, xs);
    k_bounds<<<NB256, 256, 0, stream>>>(batch, gmin, gmax);

    k_conv16<<<LAYER_BLOCKS, 256, 0, stream>>>(xs, dinv, offs, deg, csr_src, sorted, W1, b1, h1b);
    k_conv64b<1><<<LAYER_BLOCKS, 256, 0, stream>>>(h1b, dinv, offs, deg, csr_src, sorted, W2, b2,
                                                   h2b, (float*)nullptr);
    k_conv64b<0><<<LAYER_BLOCKS, 256, 0, stream>>>(h2b, dinv, offs, deg, csr_src, sorted, W2, b2,
                                                   (u32*)nullptr, agg3);
    k_pool<<<N_GRAPHS, 64, 0, stream>>>(agg3, gmin, gmax, gpool, gcnt);
    k_final<<<(N_GRAPHS * 64 + 255) / 256, 256, 0, stream>>>(gpool, gcnt, W3, b3, Wl, bl, out);
}